// Round 1
// baseline (1011.950 us; speedup 1.0000x reference)
//
#include <hip/hip_runtime.h>
#include <math.h>

#define N_NODES 100000
#define N_EDGES 1600000
#define IN_CH 512
#define HID 64
#define OUT_CH 32
#define MU 0.1f
#define EPS 1e-8f

// ---------------- MLP: f = relu(x@W1+b1)@W2 + b2 ----------------
// block 256 threads handles 64 rows. fp32, 4x4 micro-tile for GEMM1.
__global__ __launch_bounds__(256) void k_mlp(
    const float* __restrict__ x, const float* __restrict__ W1,
    const float* __restrict__ b1, const float* __restrict__ W2,
    const float* __restrict__ b2, float* __restrict__ f) {
  __shared__ float xt[64][65];    // xt[k][row]
  __shared__ float w1s[64][64];   // w1s[k][c]
  __shared__ float hs[64][65];    // h[row][k]
  __shared__ float w2s[HID * OUT_CH];
  __shared__ float b1s[HID];
  __shared__ float b2s[OUT_CH];

  const int t = threadIdx.x;
  const int r0 = blockIdx.x * 64;
  for (int i = t; i < HID * OUT_CH; i += 256) w2s[i] = W2[i];
  if (t < HID) b1s[t] = b1[t];
  if (t < OUT_CH) b2s[t] = b2[t];

  const int ty = t >> 4;   // 0..15 -> rows ty*4..+3
  const int tx = t & 15;   // 0..15 -> cols tx*4..+3
  float acc[4][4] = {{0.f}};

  for (int kc = 0; kc < IN_CH; kc += 64) {
    __syncthreads();
    #pragma unroll
    for (int i = 0; i < 4; ++i) {
      int row = ty + 16 * i;       // 0..63
      int gr = r0 + row;
      float4 v = make_float4(0.f, 0.f, 0.f, 0.f);
      if (gr < N_NODES) v = *(const float4*)&x[(size_t)gr * IN_CH + kc + tx * 4];
      xt[tx * 4 + 0][row] = v.x;
      xt[tx * 4 + 1][row] = v.y;
      xt[tx * 4 + 2][row] = v.z;
      xt[tx * 4 + 3][row] = v.w;
      // here `row` doubles as k-index for W1 staging
      *(float4*)&w1s[row][tx * 4] = *(const float4*)&W1[(size_t)(kc + row) * HID + tx * 4];
    }
    __syncthreads();
    #pragma unroll
    for (int k = 0; k < 64; ++k) {
      float4 b = *(const float4*)&w1s[k][tx * 4];
      float a0 = xt[k][ty * 4 + 0];
      float a1 = xt[k][ty * 4 + 1];
      float a2 = xt[k][ty * 4 + 2];
      float a3 = xt[k][ty * 4 + 3];
      acc[0][0] += a0 * b.x; acc[0][1] += a0 * b.y; acc[0][2] += a0 * b.z; acc[0][3] += a0 * b.w;
      acc[1][0] += a1 * b.x; acc[1][1] += a1 * b.y; acc[1][2] += a1 * b.z; acc[1][3] += a1 * b.w;
      acc[2][0] += a2 * b.x; acc[2][1] += a2 * b.y; acc[2][2] += a2 * b.z; acc[2][3] += a2 * b.w;
      acc[3][0] += a3 * b.x; acc[3][1] += a3 * b.y; acc[3][2] += a3 * b.z; acc[3][3] += a3 * b.w;
    }
  }
  __syncthreads();
  #pragma unroll
  for (int jr = 0; jr < 4; ++jr) {
    #pragma unroll
    for (int jc = 0; jc < 4; ++jc) {
      float h = acc[jr][jc] + b1s[tx * 4 + jc];
      hs[ty * 4 + jr][tx * 4 + jc] = h > 0.f ? h : 0.f;
    }
  }
  __syncthreads();
  // GEMM2: row fr = t>>2 (0..63), cols c0..c0+7
  const int fr = t >> 2;
  const int c0 = (t & 3) * 8;
  float fa[8] = {0.f};
  #pragma unroll 8
  for (int k = 0; k < HID; ++k) {
    float hv = hs[fr][k];
    #pragma unroll
    for (int j = 0; j < 8; ++j) fa[j] += hv * w2s[k * OUT_CH + c0 + j];
  }
  int gr = r0 + fr;
  if (gr < N_NODES) {
    #pragma unroll
    for (int j = 0; j < 8; ++j) f[(size_t)gr * OUT_CH + c0 + j] = fa[j] + b2s[c0 + j];
  }
}

// ---------------- CSR build ----------------
__global__ void k_hist(const int* __restrict__ src, const int* __restrict__ dst,
                       int* __restrict__ deg) {
  int e = blockIdx.x * 256 + threadIdx.x;
  if (e < N_EDGES) {
    atomicAdd(&deg[src[e]], 1);
    atomicAdd(&deg[dst[e]], 1);
  }
}

__global__ void k_offsets(const int* __restrict__ deg, int* __restrict__ counter,
                          int* __restrict__ rowstart, int* __restrict__ cursor,
                          float* __restrict__ dis, float* __restrict__ dinv) {
  int v = blockIdx.x * 256 + threadIdx.x;
  if (v < N_NODES) {
    int d = deg[v];
    int base = atomicAdd(counter, d);
    rowstart[v] = base;
    cursor[v] = base;
    float di = d > 0 ? 1.0f / (float)d : 0.0f;
    dinv[v] = di;
    dis[v] = sqrtf(di);
  }
}

__global__ void k_fill(const int* __restrict__ src, const int* __restrict__ dst,
                       int* __restrict__ cursor, int* __restrict__ adj) {
  int e = blockIdx.x * 256 + threadIdx.x;
  if (e < N_EDGES) {
    int u = src[e], v = dst[e];
    adj[atomicAdd(&cursor[u], 1)] = v;
    adj[atomicAdd(&cursor[v], 1)] = u;
  }
}

// ---------------- gs0 = f * dis ----------------
__global__ void k_gs0(const float* __restrict__ f, const float* __restrict__ dis,
                      float* __restrict__ gs) {
  int i = blockIdx.x * 256 + threadIdx.x;
  if (i < N_NODES * OUT_CH) gs[i] = f[i] * dis[i >> 5];
}

// ---------------- propagation iteration (node-centric gather) ----------------
// one wave per node; lane = slot(2) x channel(32).
template <bool FINAL>
__global__ __launch_bounds__(256) void k_prop(
    const float* __restrict__ gs_in, const float* __restrict__ f,
    const float* __restrict__ dis, const float* __restrict__ dinv,
    const int* __restrict__ rowstart, const int* __restrict__ rowend,
    const int* __restrict__ adj, float* __restrict__ out) {
  const int v = blockIdx.x * 4 + (threadIdx.x >> 6);
  const int lane = threadIdx.x & 63;
  const int c = lane & 31;
  const int slot = lane >> 5;

  const float gsv = gs_in[v * OUT_CH + c];
  const float disv = dis[v];
  const float dinvv = dinv[v];
  const int i0 = rowstart[v];
  const int i1 = rowend[v];

  float accs = 0.f;
  float acca = 0.f;
  for (int i = i0 + slot; i < i1; i += 2) {
    int u = adj[i];
    float gsu = gs_in[u * OUT_CH + c];
    float d = gsv - gsu;
    float sq = d * d;
    sq += __shfl_xor(sq, 16);
    sq += __shfl_xor(sq, 8);
    sq += __shfl_xor(sq, 4);
    sq += __shfl_xor(sq, 2);
    sq += __shfl_xor(sq, 1);
    float w = __frsqrt_rn(sqrtf(sq + EPS));  // (sq+eps)^(-1/4)
    accs += w;
    acca += w * gsu;
  }
  accs += __shfl_xor(accs, 32);
  acca += __shfl_xor(acca, 32);

  const float alpha = 1.0f / (accs * dinvv + MU);
  float r = alpha * (disv * acca) + (MU * alpha) * f[v * OUT_CH + c];

  if (FINAL) {
    float m = r;
    m = fmaxf(m, __shfl_xor(m, 16));
    m = fmaxf(m, __shfl_xor(m, 8));
    m = fmaxf(m, __shfl_xor(m, 4));
    m = fmaxf(m, __shfl_xor(m, 2));
    m = fmaxf(m, __shfl_xor(m, 1));
    float se = expf(r - m);
    se += __shfl_xor(se, 16);
    se += __shfl_xor(se, 8);
    se += __shfl_xor(se, 4);
    se += __shfl_xor(se, 2);
    se += __shfl_xor(se, 1);
    float o = r - m - logf(se);
    if (slot == 0) out[v * OUT_CH + c] = o;
  } else {
    if (slot == 0) out[v * OUT_CH + c] = r * disv;  // gs for next iteration
  }
}

extern "C" void kernel_launch(void* const* d_in, const int* in_sizes, int n_in,
                              void* d_out, int out_size, void* d_ws, size_t ws_size,
                              hipStream_t stream) {
  const float* x = (const float*)d_in[0];
  const int* ei = (const int*)d_in[1];
  const float* W1 = (const float*)d_in[2];
  const float* b1 = (const float*)d_in[3];
  const float* W2 = (const float*)d_in[4];
  const float* b2 = (const float*)d_in[5];
  float* out = (float*)d_out;
  const int* src = ei;
  const int* dst = ei + N_EDGES;

  float* f = (float*)d_ws;                  // N*32
  float* gsa = f + (size_t)N_NODES * 32;    // N*32
  float* gsb = gsa + (size_t)N_NODES * 32;  // N*32
  float* dis = gsb + (size_t)N_NODES * 32;  // N
  float* dinv = dis + N_NODES;              // N
  int* deg = (int*)(dinv + N_NODES);        // N
  int* counter = deg + N_NODES;             // 1 (+3 pad)
  int* rowstart = counter + 4;              // N
  int* cursor = rowstart + N_NODES;         // N
  int* adj = cursor + N_NODES;              // 2E

  hipMemsetAsync(deg, 0, (N_NODES + 4) * sizeof(int), stream);
  k_hist<<<(N_EDGES + 255) / 256, 256, 0, stream>>>(src, dst, deg);
  k_offsets<<<(N_NODES + 255) / 256, 256, 0, stream>>>(deg, counter, rowstart, cursor, dis, dinv);
  k_fill<<<(N_EDGES + 255) / 256, 256, 0, stream>>>(src, dst, cursor, adj);
  k_mlp<<<(N_NODES + 63) / 64, 256, 0, stream>>>(x, W1, b1, W2, b2, f);
  k_gs0<<<(N_NODES * OUT_CH + 255) / 256, 256, 0, stream>>>(f, dis, gsa);
  k_prop<false><<<N_NODES / 4, 256, 0, stream>>>(gsa, f, dis, dinv, rowstart, cursor, adj, gsb);
  k_prop<true><<<N_NODES / 4, 256, 0, stream>>>(gsb, f, dis, dinv, rowstart, cursor, adj, out);
}

// Round 2
// 767.902 us; speedup vs baseline: 1.3178x; 1.3178x over previous
//
#include <hip/hip_runtime.h>
#include <math.h>

#define N_NODES 100000
#define N_EDGES 1600000
#define IN_CH 512
#define HID 64
#define OUT_CH 32
#define MU 0.1f
#define EPS 1e-8f

// ---------------- MLP: f = relu(x@W1+b1)@W2 + b2, fused gs0 = f*dis ----------------
// block 256 threads handles 64 rows. fp32, 4x4 micro-tile for GEMM1.
__global__ __launch_bounds__(256) void k_mlp(
    const float* __restrict__ x, const float* __restrict__ W1,
    const float* __restrict__ b1, const float* __restrict__ W2,
    const float* __restrict__ b2, const int* __restrict__ deg,
    float* __restrict__ f, float* __restrict__ gs) {
  __shared__ float xt[64][65];    // xt[k][row]
  __shared__ float w1s[64][64];   // w1s[k][c]
  __shared__ float hs[64][65];    // h[row][k]
  __shared__ float w2s[HID * OUT_CH];
  __shared__ float b1s[HID];
  __shared__ float b2s[OUT_CH];

  const int t = threadIdx.x;
  const int r0 = blockIdx.x * 64;
  for (int i = t; i < HID * OUT_CH; i += 256) w2s[i] = W2[i];
  if (t < HID) b1s[t] = b1[t];
  if (t < OUT_CH) b2s[t] = b2[t];

  const int ty = t >> 4;   // 0..15 -> rows ty*4..+3
  const int tx = t & 15;   // 0..15 -> cols tx*4..+3
  float acc[4][4] = {{0.f}};

  for (int kc = 0; kc < IN_CH; kc += 64) {
    __syncthreads();
    #pragma unroll
    for (int i = 0; i < 4; ++i) {
      int row = ty + 16 * i;       // 0..63
      int gr = r0 + row;
      float4 v = make_float4(0.f, 0.f, 0.f, 0.f);
      if (gr < N_NODES) v = *(const float4*)&x[(size_t)gr * IN_CH + kc + tx * 4];
      xt[tx * 4 + 0][row] = v.x;
      xt[tx * 4 + 1][row] = v.y;
      xt[tx * 4 + 2][row] = v.z;
      xt[tx * 4 + 3][row] = v.w;
      // here `row` doubles as k-index for W1 staging
      *(float4*)&w1s[row][tx * 4] = *(const float4*)&W1[(size_t)(kc + row) * HID + tx * 4];
    }
    __syncthreads();
    #pragma unroll
    for (int k = 0; k < 64; ++k) {
      float4 b = *(const float4*)&w1s[k][tx * 4];
      float a0 = xt[k][ty * 4 + 0];
      float a1 = xt[k][ty * 4 + 1];
      float a2 = xt[k][ty * 4 + 2];
      float a3 = xt[k][ty * 4 + 3];
      acc[0][0] += a0 * b.x; acc[0][1] += a0 * b.y; acc[0][2] += a0 * b.z; acc[0][3] += a0 * b.w;
      acc[1][0] += a1 * b.x; acc[1][1] += a1 * b.y; acc[1][2] += a1 * b.z; acc[1][3] += a1 * b.w;
      acc[2][0] += a2 * b.x; acc[2][1] += a2 * b.y; acc[2][2] += a2 * b.z; acc[2][3] += a2 * b.w;
      acc[3][0] += a3 * b.x; acc[3][1] += a3 * b.y; acc[3][2] += a3 * b.z; acc[3][3] += a3 * b.w;
    }
  }
  __syncthreads();
  #pragma unroll
  for (int jr = 0; jr < 4; ++jr) {
    #pragma unroll
    for (int jc = 0; jc < 4; ++jc) {
      float h = acc[jr][jc] + b1s[tx * 4 + jc];
      hs[ty * 4 + jr][tx * 4 + jc] = h > 0.f ? h : 0.f;
    }
  }
  __syncthreads();
  // GEMM2: row fr = t>>2 (0..63), cols c0..c0+7
  const int fr = t >> 2;
  const int c0 = (t & 3) * 8;
  float fa[8] = {0.f};
  #pragma unroll 8
  for (int k = 0; k < HID; ++k) {
    float hv = hs[fr][k];
    #pragma unroll
    for (int j = 0; j < 8; ++j) fa[j] += hv * w2s[k * OUT_CH + c0 + j];
  }
  int gr = r0 + fr;
  if (gr < N_NODES) {
    int d = deg[gr];
    float di = d > 0 ? 1.0f / (float)d : 0.0f;
    float disv = sqrtf(di);
    #pragma unroll
    for (int j = 0; j < 8; ++j) {
      float fv = fa[j] + b2s[c0 + j];
      f[(size_t)gr * OUT_CH + c0 + j] = fv;
      gs[(size_t)gr * OUT_CH + c0 + j] = fv * disv;
    }
  }
}

// ---------------- CSR build ----------------
// Pass 1: histogram + record each endpoint's slot (atomics with return,
// coalesced pos writes). Pass 2 (fill) then needs NO atomics.
__global__ void k_hist(const int* __restrict__ src, const int* __restrict__ dst,
                       int* __restrict__ deg, int* __restrict__ pos_s,
                       int* __restrict__ pos_d) {
  int e = blockIdx.x * 256 + threadIdx.x;
  if (e < N_EDGES) {
    pos_s[e] = atomicAdd(&deg[src[e]], 1);
    pos_d[e] = atomicAdd(&deg[dst[e]], 1);
  }
}

__global__ void k_offsets(const int* __restrict__ deg, int* __restrict__ counter,
                          int* __restrict__ rowstart) {
  int v = blockIdx.x * 256 + threadIdx.x;
  if (v < N_NODES) rowstart[v] = atomicAdd(counter, deg[v]);
}

__global__ void k_fill(const int* __restrict__ src, const int* __restrict__ dst,
                       const int* __restrict__ pos_s, const int* __restrict__ pos_d,
                       const int* __restrict__ rowstart, int* __restrict__ adj) {
  int e = blockIdx.x * 256 + threadIdx.x;
  if (e < N_EDGES) {
    int u = src[e], v = dst[e];
    adj[rowstart[u] + pos_s[e]] = v;
    adj[rowstart[v] + pos_d[e]] = u;
  }
}

// ---------------- propagation iteration (node-centric gather) ----------------
// one wave per node; lane = slot(2) x channel(32).
template <bool FINAL>
__global__ __launch_bounds__(256) void k_prop(
    const float* __restrict__ gs_in, const float* __restrict__ f,
    const int* __restrict__ deg, const int* __restrict__ rowstart,
    const int* __restrict__ adj, float* __restrict__ out) {
  const int v = blockIdx.x * 4 + (threadIdx.x >> 6);
  const int lane = threadIdx.x & 63;
  const int c = lane & 31;
  const int slot = lane >> 5;

  const float gsv = gs_in[v * OUT_CH + c];
  const int dg = deg[v];
  const float dinvv = dg > 0 ? 1.0f / (float)dg : 0.0f;
  const float disv = sqrtf(dinvv);
  const int i0 = rowstart[v];
  const int i1 = i0 + dg;

  float accs = 0.f;
  float acca = 0.f;
  for (int i = i0 + slot; i < i1; i += 2) {
    int u = adj[i];
    float gsu = gs_in[u * OUT_CH + c];
    float d = gsv - gsu;
    float sq = d * d;
    sq += __shfl_xor(sq, 16);
    sq += __shfl_xor(sq, 8);
    sq += __shfl_xor(sq, 4);
    sq += __shfl_xor(sq, 2);
    sq += __shfl_xor(sq, 1);
    float w = __frsqrt_rn(sqrtf(sq + EPS));  // (sq+eps)^(-1/4)
    accs += w;
    acca += w * gsu;
  }
  accs += __shfl_xor(accs, 32);
  acca += __shfl_xor(acca, 32);

  const float alpha = 1.0f / (accs * dinvv + MU);
  float r = alpha * (disv * acca) + (MU * alpha) * f[v * OUT_CH + c];

  if (FINAL) {
    float m = r;
    m = fmaxf(m, __shfl_xor(m, 16));
    m = fmaxf(m, __shfl_xor(m, 8));
    m = fmaxf(m, __shfl_xor(m, 4));
    m = fmaxf(m, __shfl_xor(m, 2));
    m = fmaxf(m, __shfl_xor(m, 1));
    float se = expf(r - m);
    se += __shfl_xor(se, 16);
    se += __shfl_xor(se, 8);
    se += __shfl_xor(se, 4);
    se += __shfl_xor(se, 2);
    se += __shfl_xor(se, 1);
    float o = r - m - logf(se);
    if (slot == 0) out[v * OUT_CH + c] = o;
  } else {
    if (slot == 0) out[v * OUT_CH + c] = r * disv;  // gs for next iteration
  }
}

extern "C" void kernel_launch(void* const* d_in, const int* in_sizes, int n_in,
                              void* d_out, int out_size, void* d_ws, size_t ws_size,
                              hipStream_t stream) {
  const float* x = (const float*)d_in[0];
  const int* ei = (const int*)d_in[1];
  const float* W1 = (const float*)d_in[2];
  const float* b1 = (const float*)d_in[3];
  const float* W2 = (const float*)d_in[4];
  const float* b2 = (const float*)d_in[5];
  float* out = (float*)d_out;
  const int* src = ei;
  const int* dst = ei + N_EDGES;

  float* f = (float*)d_ws;                  // N*32
  float* gsa = f + (size_t)N_NODES * 32;    // N*32
  float* gsb = gsa + (size_t)N_NODES * 32;  // N*32
  int* deg = (int*)(gsb + (size_t)N_NODES * 32);  // N
  int* counter = deg + N_NODES;             // 1 (+3 pad)
  int* rowstart = counter + 4;              // N
  int* adj = rowstart + N_NODES;            // 2E
  // pos arrays are only live during CSR build; overlay the (dead) gs buffers
  int* pos_s = (int*)gsa;                   // E ints (6.4MB < 12.8MB)
  int* pos_d = (int*)gsb;                   // E ints

  hipMemsetAsync(deg, 0, (N_NODES + 4) * sizeof(int), stream);
  k_hist<<<(N_EDGES + 255) / 256, 256, 0, stream>>>(src, dst, deg, pos_s, pos_d);
  k_offsets<<<(N_NODES + 255) / 256, 256, 0, stream>>>(deg, counter, rowstart);
  k_fill<<<(N_EDGES + 255) / 256, 256, 0, stream>>>(src, dst, pos_s, pos_d, rowstart, adj);
  k_mlp<<<(N_NODES + 63) / 64, 256, 0, stream>>>(x, W1, b1, W2, b2, deg, f, gsa);
  k_prop<false><<<N_NODES / 4, 256, 0, stream>>>(gsa, f, deg, rowstart, adj, gsb);
  k_prop<true><<<N_NODES / 4, 256, 0, stream>>>(gsb, f, deg, rowstart, adj, out);
}

// Round 3
// 533.093 us; speedup vs baseline: 1.8983x; 1.4405x over previous
//
#include <hip/hip_runtime.h>
#include <math.h>

#define N_NODES 100000
#define N_EDGES 1600000
#define IN_CH 512
#define HID 64
#define OUT_CH 32
#define MU 0.1f
#define EPS 1e-8f

// ---------------- MLP: f = relu(x@W1+b1)@W2 + b2, fused gs0 = f*dis ----------------
__global__ __launch_bounds__(256) void k_mlp(
    const float* __restrict__ x, const float* __restrict__ W1,
    const float* __restrict__ b1, const float* __restrict__ W2,
    const float* __restrict__ b2, const int* __restrict__ deg,
    float* __restrict__ f, float* __restrict__ gs) {
  __shared__ float xt[64][65];    // xt[k][row]
  __shared__ float w1s[64][64];   // w1s[k][c]
  __shared__ float hs[64][65];    // h[row][k]
  __shared__ float w2s[HID * OUT_CH];
  __shared__ float b1s[HID];
  __shared__ float b2s[OUT_CH];

  const int t = threadIdx.x;
  const int r0 = blockIdx.x * 64;
  for (int i = t; i < HID * OUT_CH; i += 256) w2s[i] = W2[i];
  if (t < HID) b1s[t] = b1[t];
  if (t < OUT_CH) b2s[t] = b2[t];

  const int ty = t >> 4;
  const int tx = t & 15;
  float acc[4][4] = {{0.f}};

  for (int kc = 0; kc < IN_CH; kc += 64) {
    __syncthreads();
    #pragma unroll
    for (int i = 0; i < 4; ++i) {
      int row = ty + 16 * i;
      int gr = r0 + row;
      float4 v = make_float4(0.f, 0.f, 0.f, 0.f);
      if (gr < N_NODES) v = *(const float4*)&x[(size_t)gr * IN_CH + kc + tx * 4];
      xt[tx * 4 + 0][row] = v.x;
      xt[tx * 4 + 1][row] = v.y;
      xt[tx * 4 + 2][row] = v.z;
      xt[tx * 4 + 3][row] = v.w;
      *(float4*)&w1s[row][tx * 4] = *(const float4*)&W1[(size_t)(kc + row) * HID + tx * 4];
    }
    __syncthreads();
    #pragma unroll
    for (int k = 0; k < 64; ++k) {
      float4 b = *(const float4*)&w1s[k][tx * 4];
      float a0 = xt[k][ty * 4 + 0];
      float a1 = xt[k][ty * 4 + 1];
      float a2 = xt[k][ty * 4 + 2];
      float a3 = xt[k][ty * 4 + 3];
      acc[0][0] += a0 * b.x; acc[0][1] += a0 * b.y; acc[0][2] += a0 * b.z; acc[0][3] += a0 * b.w;
      acc[1][0] += a1 * b.x; acc[1][1] += a1 * b.y; acc[1][2] += a1 * b.z; acc[1][3] += a1 * b.w;
      acc[2][0] += a2 * b.x; acc[2][1] += a2 * b.y; acc[2][2] += a2 * b.z; acc[2][3] += a2 * b.w;
      acc[3][0] += a3 * b.x; acc[3][1] += a3 * b.y; acc[3][2] += a3 * b.z; acc[3][3] += a3 * b.w;
    }
  }
  __syncthreads();
  #pragma unroll
  for (int jr = 0; jr < 4; ++jr) {
    #pragma unroll
    for (int jc = 0; jc < 4; ++jc) {
      float h = acc[jr][jc] + b1s[tx * 4 + jc];
      hs[ty * 4 + jr][tx * 4 + jc] = h > 0.f ? h : 0.f;
    }
  }
  __syncthreads();
  const int fr = t >> 2;
  const int c0 = (t & 3) * 8;
  float fa[8] = {0.f};
  #pragma unroll 8
  for (int k = 0; k < HID; ++k) {
    float hv = hs[fr][k];
    #pragma unroll
    for (int j = 0; j < 8; ++j) fa[j] += hv * w2s[k * OUT_CH + c0 + j];
  }
  int gr = r0 + fr;
  if (gr < N_NODES) {
    int d = deg[gr];
    float di = d > 0 ? 1.0f / (float)d : 0.0f;
    float disv = sqrtf(di);
    #pragma unroll
    for (int j = 0; j < 8; ++j) {
      float fv = fa[j] + b2s[c0 + j];
      f[(size_t)gr * OUT_CH + c0 + j] = fv;
      gs[(size_t)gr * OUT_CH + c0 + j] = fv * disv;
    }
  }
}

// ---------------- CSR build ----------------
__global__ void k_hist(const int* __restrict__ src, const int* __restrict__ dst,
                       int* __restrict__ deg, int* __restrict__ pos_s,
                       int* __restrict__ pos_d) {
  int e = blockIdx.x * 256 + threadIdx.x;
  if (e < N_EDGES) {
    pos_s[e] = atomicAdd(&deg[src[e]], 1);
    pos_d[e] = atomicAdd(&deg[dst[e]], 1);
  }
}

__global__ void k_offsets(const int* __restrict__ deg, int* __restrict__ counter,
                          int* __restrict__ rowstart) {
  int v = blockIdx.x * 256 + threadIdx.x;
  if (v < N_NODES) rowstart[v] = atomicAdd(counter, deg[v]);
}

__global__ void k_fill(const int* __restrict__ src, const int* __restrict__ dst,
                       const int* __restrict__ pos_s, const int* __restrict__ pos_d,
                       const int* __restrict__ rowstart, int* __restrict__ adj) {
  int e = blockIdx.x * 256 + threadIdx.x;
  if (e < N_EDGES) {
    int u = src[e], v = dst[e];
    adj[rowstart[u] + pos_s[e]] = v;
    adj[rowstart[v] + pos_d[e]] = u;
  }
}

// ---------------- propagation iteration (node-centric gather) ----------------
// one wave per node; lane = slot(16) x channel-group(4 x 8ch).
template <bool FINAL>
__global__ __launch_bounds__(256) void k_prop(
    const float* __restrict__ gs_in, const float* __restrict__ f,
    const int* __restrict__ deg, const int* __restrict__ rowstart,
    const int* __restrict__ adj, float* __restrict__ out) {
  const int v = blockIdx.x * 4 + (threadIdx.x >> 6);
  const int lane = threadIdx.x & 63;
  const int slot = lane >> 2;        // 0..15
  const int cg = (lane & 3) << 3;    // 0,8,16,24

  const float4 gv0 = *(const float4*)&gs_in[v * OUT_CH + cg];
  const float4 gv1 = *(const float4*)&gs_in[v * OUT_CH + cg + 4];

  const int dg = deg[v];
  const float dinvv = dg > 0 ? 1.0f / (float)dg : 0.0f;
  const float disv = sqrtf(dinvv);
  const int i0 = rowstart[v];

  float accs = 0.f;
  float acca[8] = {0.f, 0.f, 0.f, 0.f, 0.f, 0.f, 0.f, 0.f};

  for (int base = 0; base < dg; base += 16) {
    const int idx = base + slot;
    const bool valid = idx < dg;
    const int u = valid ? adj[i0 + idx] : v;
    const float4 gu0 = *(const float4*)&gs_in[u * OUT_CH + cg];
    const float4 gu1 = *(const float4*)&gs_in[u * OUT_CH + cg + 4];
    float d, sq;
    d = gv0.x - gu0.x; sq = d * d;
    d = gv0.y - gu0.y; sq = fmaf(d, d, sq);
    d = gv0.z - gu0.z; sq = fmaf(d, d, sq);
    d = gv0.w - gu0.w; sq = fmaf(d, d, sq);
    d = gv1.x - gu1.x; sq = fmaf(d, d, sq);
    d = gv1.y - gu1.y; sq = fmaf(d, d, sq);
    d = gv1.z - gu1.z; sq = fmaf(d, d, sq);
    d = gv1.w - gu1.w; sq = fmaf(d, d, sq);
    sq += __shfl_xor(sq, 1);
    sq += __shfl_xor(sq, 2);
    const float w = valid ? __frsqrt_rn(sqrtf(sq + EPS)) : 0.f;  // (sq+eps)^(-1/4)
    accs += w;
    acca[0] = fmaf(w, gu0.x, acca[0]);
    acca[1] = fmaf(w, gu0.y, acca[1]);
    acca[2] = fmaf(w, gu0.z, acca[2]);
    acca[3] = fmaf(w, gu0.w, acca[3]);
    acca[4] = fmaf(w, gu1.x, acca[4]);
    acca[5] = fmaf(w, gu1.y, acca[5]);
    acca[6] = fmaf(w, gu1.z, acca[6]);
    acca[7] = fmaf(w, gu1.w, acca[7]);
  }

  // reduce across the 16 slots (xor 4,8,16,32 preserves lane&3 = channel group)
  #pragma unroll
  for (int s = 4; s <= 32; s <<= 1) {
    accs += __shfl_xor(accs, s);
    #pragma unroll
    for (int j = 0; j < 8; ++j) acca[j] += __shfl_xor(acca[j], s);
  }

  const float alpha = 1.0f / (accs * dinvv + MU);
  const float ad = alpha * disv;
  const float ba = MU * alpha;
  const float4 fv0 = *(const float4*)&f[v * OUT_CH + cg];
  const float4 fv1 = *(const float4*)&f[v * OUT_CH + cg + 4];
  float r[8];
  r[0] = fmaf(ad, acca[0], ba * fv0.x);
  r[1] = fmaf(ad, acca[1], ba * fv0.y);
  r[2] = fmaf(ad, acca[2], ba * fv0.z);
  r[3] = fmaf(ad, acca[3], ba * fv0.w);
  r[4] = fmaf(ad, acca[4], ba * fv1.x);
  r[5] = fmaf(ad, acca[5], ba * fv1.y);
  r[6] = fmaf(ad, acca[6], ba * fv1.z);
  r[7] = fmaf(ad, acca[7], ba * fv1.w);

  if (FINAL) {
    float m = r[0];
    #pragma unroll
    for (int j = 1; j < 8; ++j) m = fmaxf(m, r[j]);
    m = fmaxf(m, __shfl_xor(m, 1));
    m = fmaxf(m, __shfl_xor(m, 2));
    float se = 0.f;
    #pragma unroll
    for (int j = 0; j < 8; ++j) se += __expf(r[j] - m);
    se += __shfl_xor(se, 1);
    se += __shfl_xor(se, 2);
    const float lse = m + __logf(se);
    if (slot == 0) {
      float4 o0 = make_float4(r[0] - lse, r[1] - lse, r[2] - lse, r[3] - lse);
      float4 o1 = make_float4(r[4] - lse, r[5] - lse, r[6] - lse, r[7] - lse);
      *(float4*)&out[v * OUT_CH + cg] = o0;
      *(float4*)&out[v * OUT_CH + cg + 4] = o1;
    }
  } else {
    if (slot == 0) {
      float4 o0 = make_float4(r[0] * disv, r[1] * disv, r[2] * disv, r[3] * disv);
      float4 o1 = make_float4(r[4] * disv, r[5] * disv, r[6] * disv, r[7] * disv);
      *(float4*)&out[v * OUT_CH + cg] = o0;
      *(float4*)&out[v * OUT_CH + cg + 4] = o1;
    }
  }
}

extern "C" void kernel_launch(void* const* d_in, const int* in_sizes, int n_in,
                              void* d_out, int out_size, void* d_ws, size_t ws_size,
                              hipStream_t stream) {
  const float* x = (const float*)d_in[0];
  const int* ei = (const int*)d_in[1];
  const float* W1 = (const float*)d_in[2];
  const float* b1 = (const float*)d_in[3];
  const float* W2 = (const float*)d_in[4];
  const float* b2 = (const float*)d_in[5];
  float* out = (float*)d_out;
  const int* src = ei;
  const int* dst = ei + N_EDGES;

  float* f = (float*)d_ws;                  // N*32
  float* gsa = f + (size_t)N_NODES * 32;    // N*32
  float* gsb = gsa + (size_t)N_NODES * 32;  // N*32
  int* deg = (int*)(gsb + (size_t)N_NODES * 32);  // N
  int* counter = deg + N_NODES;             // 1 (+3 pad)
  int* rowstart = counter + 4;              // N
  int* adj = rowstart + N_NODES;            // 2E
  int* pos_s = (int*)gsa;                   // E ints (overlay, dead during build)
  int* pos_d = (int*)gsb;                   // E ints

  hipMemsetAsync(deg, 0, (N_NODES + 4) * sizeof(int), stream);
  k_hist<<<(N_EDGES + 255) / 256, 256, 0, stream>>>(src, dst, deg, pos_s, pos_d);
  k_offsets<<<(N_NODES + 255) / 256, 256, 0, stream>>>(deg, counter, rowstart);
  k_fill<<<(N_EDGES + 255) / 256, 256, 0, stream>>>(src, dst, pos_s, pos_d, rowstart, adj);
  k_mlp<<<(N_NODES + 63) / 64, 256, 0, stream>>>(x, W1, b1, W2, b2, deg, f, gsa);
  k_prop<false><<<N_NODES / 4, 256, 0, stream>>>(gsa, f, deg, rowstart, adj, gsb);
  k_prop<true><<<N_NODES / 4, 256, 0, stream>>>(gsb, f, deg, rowstart, adj, out);
}

// Round 4
// 428.385 us; speedup vs baseline: 2.3622x; 1.2444x over previous
//
#include <hip/hip_runtime.h>
#include <hip/hip_bf16.h>
#include <math.h>

#define N_NODES 100000
#define N_EDGES 1600000
#define IN_CH 512
#define HID 64
#define OUT_CH 32
#define MU 0.1f
#define EPS 1e-8f

typedef short bf16x8 __attribute__((ext_vector_type(8)));
typedef float f32x4 __attribute__((ext_vector_type(4)));

__device__ __forceinline__ short f2bf(float f) {
  __hip_bfloat16 h = __float2bfloat16(f);
  return *reinterpret_cast<short*>(&h);
}

// ---------------- prep: W1 -> w1t[c][k] bf16, W2 -> w2t[c][k] bf16 ----------------
__global__ void k_prep(const float* __restrict__ W1, const float* __restrict__ W2,
                       short* __restrict__ w1t, short* __restrict__ w2t) {
  int i = blockIdx.x * 256 + threadIdx.x;
  if (i < IN_CH * HID) {
    int k = i / HID, c = i % HID;
    w1t[c * IN_CH + k] = f2bf(W1[i]);
  } else if (i < IN_CH * HID + HID * OUT_CH) {
    int j = i - IN_CH * HID;
    int k = j / OUT_CH, c = j % OUT_CH;
    w2t[c * HID + k] = f2bf(W2[j]);
  }
}

// ---------------- MLP via MFMA: f = relu(x@W1+b1)@W2 + b2, fused gs0 = f*dis ----
// 256 threads = 4 waves; each wave owns a 16-row band. 64 rows/block.
__global__ __launch_bounds__(256) void k_mlp(
    const float* __restrict__ x, const short* __restrict__ w1t,
    const float* __restrict__ b1, const short* __restrict__ w2t,
    const float* __restrict__ b2, const int* __restrict__ deg,
    float* __restrict__ f, float* __restrict__ gs) {
  __shared__ short ht[4][16][72];  // per-wave 16x64 bf16 h-tile, +8 pad

  const int t = threadIdx.x;
  const int w = t >> 6;
  const int l = t & 63;
  const int lr = l & 15;   // A row-in-band / B col (lane&15)
  const int kq = l >> 4;   // k-quad 0..3

  const int band = blockIdx.x * 64 + w * 16;
  const int gr = band + lr;
  const int grl = gr < N_NODES ? gr : N_NODES - 1;  // clamp for pad rows

  // ---- GEMM1: h[16][64] = x_band @ W1 ----
  f32x4 acc1[4] = {};
  const float* xrow = x + (size_t)grl * IN_CH + kq * 8;
  #pragma unroll 4
  for (int ksub = 0; ksub < 16; ++ksub) {
    float4 alo = *(const float4*)(xrow + ksub * 32);
    float4 ahi = *(const float4*)(xrow + ksub * 32 + 4);
    bf16x8 a;
    a[0] = f2bf(alo.x); a[1] = f2bf(alo.y); a[2] = f2bf(alo.z); a[3] = f2bf(alo.w);
    a[4] = f2bf(ahi.x); a[5] = f2bf(ahi.y); a[6] = f2bf(ahi.z); a[7] = f2bf(ahi.w);
    #pragma unroll
    for (int ct = 0; ct < 4; ++ct) {
      const int c = ct * 16 + lr;
      bf16x8 b = *(const bf16x8*)&w1t[c * IN_CH + ksub * 32 + kq * 8];
      acc1[ct] = __builtin_amdgcn_mfma_f32_16x16x32_bf16(a, b, acc1[ct], 0, 0, 0);
    }
  }

  // ---- bias + relu -> bf16 LDS tile (C layout: col=lane&15, row=kq*4+r) ----
  #pragma unroll
  for (int ct = 0; ct < 4; ++ct) {
    const int c = ct * 16 + lr;
    const float bb = b1[c];
    #pragma unroll
    for (int r = 0; r < 4; ++r) {
      float h = acc1[ct][r] + bb;
      ht[w][kq * 4 + r][c] = f2bf(h > 0.f ? h : 0.f);
    }
  }
  __syncthreads();

  // ---- GEMM2: f[16][32] = h @ W2 ----
  f32x4 acc2[2] = {};
  #pragma unroll
  for (int ks = 0; ks < 2; ++ks) {
    bf16x8 a2 = *(const bf16x8*)&ht[w][lr][ks * 32 + kq * 8];
    #pragma unroll
    for (int ct = 0; ct < 2; ++ct) {
      const int c = ct * 16 + lr;
      bf16x8 b = *(const bf16x8*)&w2t[c * HID + ks * 32 + kq * 8];
      acc2[ct] = __builtin_amdgcn_mfma_f32_16x16x32_bf16(a2, b, acc2[ct], 0, 0, 0);
    }
  }

  // ---- epilogue: f += b2; gs = f * dis ----
  #pragma unroll
  for (int r = 0; r < 4; ++r) {
    const int gr2 = band + kq * 4 + r;
    if (gr2 < N_NODES) {
      const int d = deg[gr2];
      const float di = d > 0 ? 1.0f / (float)d : 0.0f;
      const float disv = sqrtf(di);
      #pragma unroll
      for (int ct = 0; ct < 2; ++ct) {
        const int c = ct * 16 + lr;
        const float fv = acc2[ct][r] + b2[c];
        f[(size_t)gr2 * OUT_CH + c] = fv;
        gs[(size_t)gr2 * OUT_CH + c] = fv * disv;
      }
    }
  }
}

// ---------------- CSR build ----------------
__global__ void k_hist(const int* __restrict__ src, const int* __restrict__ dst,
                       int* __restrict__ deg, int* __restrict__ pos_s,
                       int* __restrict__ pos_d) {
  int e = blockIdx.x * 256 + threadIdx.x;
  if (e < N_EDGES) {
    pos_s[e] = atomicAdd(&deg[src[e]], 1);
    pos_d[e] = atomicAdd(&deg[dst[e]], 1);
  }
}

__global__ void k_offsets(const int* __restrict__ deg, int* __restrict__ counter,
                          int* __restrict__ rowstart) {
  int v = blockIdx.x * 256 + threadIdx.x;
  if (v < N_NODES) rowstart[v] = atomicAdd(counter, deg[v]);
}

__global__ void k_fill(const int* __restrict__ src, const int* __restrict__ dst,
                       const int* __restrict__ pos_s, const int* __restrict__ pos_d,
                       const int* __restrict__ rowstart, int* __restrict__ adj) {
  int e = blockIdx.x * 256 + threadIdx.x;
  if (e < N_EDGES) {
    int u = src[e], v = dst[e];
    adj[rowstart[u] + pos_s[e]] = v;
    adj[rowstart[v] + pos_d[e]] = u;
  }
}

// ---------------- propagation iteration (node-centric gather) ----------------
// one wave per node; lane = slot(16) x channel-group(4 x 8ch).
template <bool FINAL>
__global__ __launch_bounds__(256) void k_prop(
    const float* __restrict__ gs_in, const float* __restrict__ f,
    const int* __restrict__ deg, const int* __restrict__ rowstart,
    const int* __restrict__ adj, float* __restrict__ out) {
  const int v = blockIdx.x * 4 + (threadIdx.x >> 6);
  const int lane = threadIdx.x & 63;
  const int slot = lane >> 2;        // 0..15
  const int cg = (lane & 3) << 3;    // 0,8,16,24

  const float4 gv0 = *(const float4*)&gs_in[v * OUT_CH + cg];
  const float4 gv1 = *(const float4*)&gs_in[v * OUT_CH + cg + 4];

  const int dg = deg[v];
  const float dinvv = dg > 0 ? 1.0f / (float)dg : 0.0f;
  const float disv = sqrtf(dinvv);
  const int i0 = rowstart[v];

  float accs = 0.f;
  float acca[8] = {0.f, 0.f, 0.f, 0.f, 0.f, 0.f, 0.f, 0.f};

  for (int base = 0; base < dg; base += 16) {
    const int idx = base + slot;
    const bool valid = idx < dg;
    const int u = valid ? adj[i0 + idx] : v;
    const float4 gu0 = *(const float4*)&gs_in[u * OUT_CH + cg];
    const float4 gu1 = *(const float4*)&gs_in[u * OUT_CH + cg + 4];
    float d, sq;
    d = gv0.x - gu0.x; sq = d * d;
    d = gv0.y - gu0.y; sq = fmaf(d, d, sq);
    d = gv0.z - gu0.z; sq = fmaf(d, d, sq);
    d = gv0.w - gu0.w; sq = fmaf(d, d, sq);
    d = gv1.x - gu1.x; sq = fmaf(d, d, sq);
    d = gv1.y - gu1.y; sq = fmaf(d, d, sq);
    d = gv1.z - gu1.z; sq = fmaf(d, d, sq);
    d = gv1.w - gu1.w; sq = fmaf(d, d, sq);
    sq += __shfl_xor(sq, 1);
    sq += __shfl_xor(sq, 2);
    const float w = valid ? __frsqrt_rn(sqrtf(sq + EPS)) : 0.f;  // (sq+eps)^(-1/4)
    accs += w;
    acca[0] = fmaf(w, gu0.x, acca[0]);
    acca[1] = fmaf(w, gu0.y, acca[1]);
    acca[2] = fmaf(w, gu0.z, acca[2]);
    acca[3] = fmaf(w, gu0.w, acca[3]);
    acca[4] = fmaf(w, gu1.x, acca[4]);
    acca[5] = fmaf(w, gu1.y, acca[5]);
    acca[6] = fmaf(w, gu1.z, acca[6]);
    acca[7] = fmaf(w, gu1.w, acca[7]);
  }

  #pragma unroll
  for (int s = 4; s <= 32; s <<= 1) {
    accs += __shfl_xor(accs, s);
    #pragma unroll
    for (int j = 0; j < 8; ++j) acca[j] += __shfl_xor(acca[j], s);
  }

  const float alpha = 1.0f / (accs * dinvv + MU);
  const float ad = alpha * disv;
  const float ba = MU * alpha;
  const float4 fv0 = *(const float4*)&f[v * OUT_CH + cg];
  const float4 fv1 = *(const float4*)&f[v * OUT_CH + cg + 4];
  float r[8];
  r[0] = fmaf(ad, acca[0], ba * fv0.x);
  r[1] = fmaf(ad, acca[1], ba * fv0.y);
  r[2] = fmaf(ad, acca[2], ba * fv0.z);
  r[3] = fmaf(ad, acca[3], ba * fv0.w);
  r[4] = fmaf(ad, acca[4], ba * fv1.x);
  r[5] = fmaf(ad, acca[5], ba * fv1.y);
  r[6] = fmaf(ad, acca[6], ba * fv1.z);
  r[7] = fmaf(ad, acca[7], ba * fv1.w);

  if (FINAL) {
    float m = r[0];
    #pragma unroll
    for (int j = 1; j < 8; ++j) m = fmaxf(m, r[j]);
    m = fmaxf(m, __shfl_xor(m, 1));
    m = fmaxf(m, __shfl_xor(m, 2));
    float se = 0.f;
    #pragma unroll
    for (int j = 0; j < 8; ++j) se += __expf(r[j] - m);
    se += __shfl_xor(se, 1);
    se += __shfl_xor(se, 2);
    const float lse = m + __logf(se);
    if (slot == 0) {
      float4 o0 = make_float4(r[0] - lse, r[1] - lse, r[2] - lse, r[3] - lse);
      float4 o1 = make_float4(r[4] - lse, r[5] - lse, r[6] - lse, r[7] - lse);
      *(float4*)&out[v * OUT_CH + cg] = o0;
      *(float4*)&out[v * OUT_CH + cg + 4] = o1;
    }
  } else {
    if (slot == 0) {
      float4 o0 = make_float4(r[0] * disv, r[1] * disv, r[2] * disv, r[3] * disv);
      float4 o1 = make_float4(r[4] * disv, r[5] * disv, r[6] * disv, r[7] * disv);
      *(float4*)&out[v * OUT_CH + cg] = o0;
      *(float4*)&out[v * OUT_CH + cg + 4] = o1;
    }
  }
}

extern "C" void kernel_launch(void* const* d_in, const int* in_sizes, int n_in,
                              void* d_out, int out_size, void* d_ws, size_t ws_size,
                              hipStream_t stream) {
  const float* x = (const float*)d_in[0];
  const int* ei = (const int*)d_in[1];
  const float* W1 = (const float*)d_in[2];
  const float* b1 = (const float*)d_in[3];
  const float* W2 = (const float*)d_in[4];
  const float* b2 = (const float*)d_in[5];
  float* out = (float*)d_out;
  const int* src = ei;
  const int* dst = ei + N_EDGES;

  float* f = (float*)d_ws;                  // N*32
  float* gsa = f + (size_t)N_NODES * 32;    // N*32
  float* gsb = gsa + (size_t)N_NODES * 32;  // N*32
  int* deg = (int*)(gsb + (size_t)N_NODES * 32);  // N
  int* counter = deg + N_NODES;             // 1 (+3 pad)
  int* rowstart = counter + 4;              // N
  int* adj = rowstart + N_NODES;            // 2E
  short* w1t = (short*)(adj + 2 * N_EDGES); // 512*64 bf16
  short* w2t = w1t + IN_CH * HID;           // 64*32 bf16
  int* pos_s = (int*)gsa;                   // overlay (dead during build)
  int* pos_d = (int*)gsb;

  hipMemsetAsync(deg, 0, (N_NODES + 4) * sizeof(int), stream);
  k_prep<<<(IN_CH * HID + HID * OUT_CH + 255) / 256, 256, 0, stream>>>(W1, W2, w1t, w2t);
  k_hist<<<(N_EDGES + 255) / 256, 256, 0, stream>>>(src, dst, deg, pos_s, pos_d);
  k_offsets<<<(N_NODES + 255) / 256, 256, 0, stream>>>(deg, counter, rowstart);
  k_fill<<<(N_EDGES + 255) / 256, 256, 0, stream>>>(src, dst, pos_s, pos_d, rowstart, adj);
  k_mlp<<<(N_NODES + 63) / 64, 256, 0, stream>>>(x, w1t, b1, w2t, b2, deg, f, gsa);
  k_prop<false><<<N_NODES / 4, 256, 0, stream>>>(gsa, f, deg, rowstart, adj, gsb);
  k_prop<true><<<N_NODES / 4, 256, 0, stream>>>(gsb, f, deg, rowstart, adj, out);
}

// Round 5
// 414.763 us; speedup vs baseline: 2.4398x; 1.0328x over previous
//
#include <hip/hip_runtime.h>
#include <hip/hip_bf16.h>
#include <math.h>

#define N_NODES 100000
#define N_EDGES 1600000
#define IN_CH 512
#define HID 64
#define OUT_CH 32
#define MU 0.1f
#define EPS 1e-8f

#define NB 391           // ceil(N_NODES/256)
#define HE (2 * N_EDGES) // 3.2M endpoints
#define EPT 10
#define HSTRIDE (HE / EPT) // 320000

typedef short bf16x8 __attribute__((ext_vector_type(8)));
typedef float f32x4 __attribute__((ext_vector_type(4)));

__device__ __forceinline__ short f2bf(float f) {
  __hip_bfloat16 h = __float2bfloat16(f);
  return *reinterpret_cast<short*>(&h);
}

// ---------------- prep: W1 -> w1t[c][k] bf16, W2 -> w2t[c][k] bf16 ----------------
__global__ void k_prep(const float* __restrict__ W1, const float* __restrict__ W2,
                       short* __restrict__ w1t, short* __restrict__ w2t) {
  int i = blockIdx.x * 256 + threadIdx.x;
  if (i < IN_CH * HID) {
    int k = i / HID, c = i % HID;
    w1t[c * IN_CH + k] = f2bf(W1[i]);
  } else if (i < IN_CH * HID + HID * OUT_CH) {
    int j = i - IN_CH * HID;
    int k = j / OUT_CH, c = j % OUT_CH;
    w2t[c * HID + k] = f2bf(W2[j]);
  }
}

// ---------------- MLP via MFMA (unchanged from R3) ----------------
__global__ __launch_bounds__(256) void k_mlp(
    const float* __restrict__ x, const short* __restrict__ w1t,
    const float* __restrict__ b1, const short* __restrict__ w2t,
    const float* __restrict__ b2, const int* __restrict__ deg,
    float* __restrict__ f, float* __restrict__ gs) {
  __shared__ short ht[4][16][72];

  const int t = threadIdx.x;
  const int w = t >> 6;
  const int l = t & 63;
  const int lr = l & 15;
  const int kq = l >> 4;

  const int band = blockIdx.x * 64 + w * 16;
  const int gr = band + lr;
  const int grl = gr < N_NODES ? gr : N_NODES - 1;

  f32x4 acc1[4] = {};
  const float* xrow = x + (size_t)grl * IN_CH + kq * 8;
  #pragma unroll 4
  for (int ksub = 0; ksub < 16; ++ksub) {
    float4 alo = *(const float4*)(xrow + ksub * 32);
    float4 ahi = *(const float4*)(xrow + ksub * 32 + 4);
    bf16x8 a;
    a[0] = f2bf(alo.x); a[1] = f2bf(alo.y); a[2] = f2bf(alo.z); a[3] = f2bf(alo.w);
    a[4] = f2bf(ahi.x); a[5] = f2bf(ahi.y); a[6] = f2bf(ahi.z); a[7] = f2bf(ahi.w);
    #pragma unroll
    for (int ct = 0; ct < 4; ++ct) {
      const int c = ct * 16 + lr;
      bf16x8 b = *(const bf16x8*)&w1t[c * IN_CH + ksub * 32 + kq * 8];
      acc1[ct] = __builtin_amdgcn_mfma_f32_16x16x32_bf16(a, b, acc1[ct], 0, 0, 0);
    }
  }

  #pragma unroll
  for (int ct = 0; ct < 4; ++ct) {
    const int c = ct * 16 + lr;
    const float bb = b1[c];
    #pragma unroll
    for (int r = 0; r < 4; ++r) {
      float h = acc1[ct][r] + bb;
      ht[w][kq * 4 + r][c] = f2bf(h > 0.f ? h : 0.f);
    }
  }
  __syncthreads();

  f32x4 acc2[2] = {};
  #pragma unroll
  for (int ks = 0; ks < 2; ++ks) {
    bf16x8 a2 = *(const bf16x8*)&ht[w][lr][ks * 32 + kq * 8];
    #pragma unroll
    for (int ct = 0; ct < 2; ++ct) {
      const int c = ct * 16 + lr;
      bf16x8 b = *(const bf16x8*)&w2t[c * HID + ks * 32 + kq * 8];
      acc2[ct] = __builtin_amdgcn_mfma_f32_16x16x32_bf16(a2, b, acc2[ct], 0, 0, 0);
    }
  }

  #pragma unroll
  for (int r = 0; r < 4; ++r) {
    const int gr2 = band + kq * 4 + r;
    if (gr2 < N_NODES) {
      const int d = deg[gr2];
      const float di = d > 0 ? 1.0f / (float)d : 0.0f;
      const float disv = sqrtf(di);
      #pragma unroll
      for (int ct = 0; ct < 2; ++ct) {
        const int c = ct * 16 + lr;
        const float fv = acc2[ct][r] + b2[c];
        f[(size_t)gr2 * OUT_CH + c] = fv;
        gs[(size_t)gr2 * OUT_CH + c] = fv * disv;
      }
    }
  }
}

// ---------------- CSR build ----------------
// hist over flat endpoint array (ei = [src;dst]); EPT=10 for atomic MLP.
__global__ __launch_bounds__(256) void k_hist(const int* __restrict__ ends,
                                              int* __restrict__ deg,
                                              int* __restrict__ pos) {
  const int tid = blockIdx.x * 256 + threadIdx.x;
  int u[EPT];
  #pragma unroll
  for (int j = 0; j < EPT; ++j) u[j] = ends[tid + j * HSTRIDE];
  int p[EPT];
  #pragma unroll
  for (int j = 0; j < EPT; ++j) p[j] = atomicAdd(&deg[u[j]], 1);
  #pragma unroll
  for (int j = 0; j < EPT; ++j) pos[tid + j * HSTRIDE] = p[j];
}

// deg -> rowstart via deterministic 3-step scan (no same-address atomics)
__global__ __launch_bounds__(256) void k_bsum(const int* __restrict__ deg,
                                              int* __restrict__ blocksum) {
  int v = blockIdx.x * 256 + threadIdx.x;
  int d = v < N_NODES ? deg[v] : 0;
  #pragma unroll
  for (int s = 1; s < 64; s <<= 1) d += __shfl_xor(d, s);
  __shared__ int ws[4];
  if ((threadIdx.x & 63) == 0) ws[threadIdx.x >> 6] = d;
  __syncthreads();
  if (threadIdx.x == 0) blocksum[blockIdx.x] = ws[0] + ws[1] + ws[2] + ws[3];
}

__global__ __launch_bounds__(512) void k_scan1(const int* __restrict__ blocksum,
                                               int* __restrict__ blockbase) {
  __shared__ int sh[512];
  const int t = threadIdx.x;
  int vv = t < NB ? blocksum[t] : 0;
  sh[t] = vv;
  __syncthreads();
  for (int s = 1; s < 512; s <<= 1) {
    int add = t >= s ? sh[t - s] : 0;
    __syncthreads();
    sh[t] += add;
    __syncthreads();
  }
  if (t < NB) blockbase[t] = sh[t] - vv;  // exclusive
}

__global__ __launch_bounds__(256) void k_rowstart(const int* __restrict__ deg,
                                                  const int* __restrict__ blockbase,
                                                  int* __restrict__ rowstart) {
  __shared__ int sh[256];
  const int t = threadIdx.x;
  const int v = blockIdx.x * 256 + t;
  int d = v < N_NODES ? deg[v] : 0;
  sh[t] = d;
  __syncthreads();
  for (int s = 1; s < 256; s <<= 1) {
    int add = t >= s ? sh[t - s] : 0;
    __syncthreads();
    sh[t] += add;
    __syncthreads();
  }
  if (v < N_NODES) rowstart[v] = blockbase[blockIdx.x] + sh[t] - d;
}

__global__ __launch_bounds__(256) void k_fill(const int* __restrict__ ends,
                                              const int* __restrict__ pos,
                                              const int* __restrict__ rowstart,
                                              int* __restrict__ adj) {
  const int tid = blockIdx.x * 256 + threadIdx.x;
  #pragma unroll
  for (int j = 0; j < EPT; ++j) {
    const int i = tid + j * HSTRIDE;
    const int u = ends[i];
    // neighbor = other endpoint; i<N_EDGES is wave-uniform (HSTRIDE-aligned chunks)
    const int nb = ends[i < N_EDGES ? i + N_EDGES : i - N_EDGES];
    adj[rowstart[u] + pos[i]] = nb;
  }
}

// ---------------- propagation iteration (unchanged from R3) ----------------
template <bool FINAL>
__global__ __launch_bounds__(256) void k_prop(
    const float* __restrict__ gs_in, const float* __restrict__ f,
    const int* __restrict__ deg, const int* __restrict__ rowstart,
    const int* __restrict__ adj, float* __restrict__ out) {
  const int v = blockIdx.x * 4 + (threadIdx.x >> 6);
  const int lane = threadIdx.x & 63;
  const int slot = lane >> 2;
  const int cg = (lane & 3) << 3;

  const float4 gv0 = *(const float4*)&gs_in[v * OUT_CH + cg];
  const float4 gv1 = *(const float4*)&gs_in[v * OUT_CH + cg + 4];

  const int dg = deg[v];
  const float dinvv = dg > 0 ? 1.0f / (float)dg : 0.0f;
  const float disv = sqrtf(dinvv);
  const int i0 = rowstart[v];

  float accs = 0.f;
  float acca[8] = {0.f, 0.f, 0.f, 0.f, 0.f, 0.f, 0.f, 0.f};

  for (int base = 0; base < dg; base += 16) {
    const int idx = base + slot;
    const bool valid = idx < dg;
    const int u = valid ? adj[i0 + idx] : v;
    const float4 gu0 = *(const float4*)&gs_in[u * OUT_CH + cg];
    const float4 gu1 = *(const float4*)&gs_in[u * OUT_CH + cg + 4];
    float d, sq;
    d = gv0.x - gu0.x; sq = d * d;
    d = gv0.y - gu0.y; sq = fmaf(d, d, sq);
    d = gv0.z - gu0.z; sq = fmaf(d, d, sq);
    d = gv0.w - gu0.w; sq = fmaf(d, d, sq);
    d = gv1.x - gu1.x; sq = fmaf(d, d, sq);
    d = gv1.y - gu1.y; sq = fmaf(d, d, sq);
    d = gv1.z - gu1.z; sq = fmaf(d, d, sq);
    d = gv1.w - gu1.w; sq = fmaf(d, d, sq);
    sq += __shfl_xor(sq, 1);
    sq += __shfl_xor(sq, 2);
    const float w = valid ? __frsqrt_rn(sqrtf(sq + EPS)) : 0.f;
    accs += w;
    acca[0] = fmaf(w, gu0.x, acca[0]);
    acca[1] = fmaf(w, gu0.y, acca[1]);
    acca[2] = fmaf(w, gu0.z, acca[2]);
    acca[3] = fmaf(w, gu0.w, acca[3]);
    acca[4] = fmaf(w, gu1.x, acca[4]);
    acca[5] = fmaf(w, gu1.y, acca[5]);
    acca[6] = fmaf(w, gu1.z, acca[6]);
    acca[7] = fmaf(w, gu1.w, acca[7]);
  }

  #pragma unroll
  for (int s = 4; s <= 32; s <<= 1) {
    accs += __shfl_xor(accs, s);
    #pragma unroll
    for (int j = 0; j < 8; ++j) acca[j] += __shfl_xor(acca[j], s);
  }

  const float alpha = 1.0f / (accs * dinvv + MU);
  const float ad = alpha * disv;
  const float ba = MU * alpha;
  const float4 fv0 = *(const float4*)&f[v * OUT_CH + cg];
  const float4 fv1 = *(const float4*)&f[v * OUT_CH + cg + 4];
  float r[8];
  r[0] = fmaf(ad, acca[0], ba * fv0.x);
  r[1] = fmaf(ad, acca[1], ba * fv0.y);
  r[2] = fmaf(ad, acca[2], ba * fv0.z);
  r[3] = fmaf(ad, acca[3], ba * fv0.w);
  r[4] = fmaf(ad, acca[4], ba * fv1.x);
  r[5] = fmaf(ad, acca[5], ba * fv1.y);
  r[6] = fmaf(ad, acca[6], ba * fv1.z);
  r[7] = fmaf(ad, acca[7], ba * fv1.w);

  if (FINAL) {
    float m = r[0];
    #pragma unroll
    for (int j = 1; j < 8; ++j) m = fmaxf(m, r[j]);
    m = fmaxf(m, __shfl_xor(m, 1));
    m = fmaxf(m, __shfl_xor(m, 2));
    float se = 0.f;
    #pragma unroll
    for (int j = 0; j < 8; ++j) se += __expf(r[j] - m);
    se += __shfl_xor(se, 1);
    se += __shfl_xor(se, 2);
    const float lse = m + __logf(se);
    if (slot == 0) {
      float4 o0 = make_float4(r[0] - lse, r[1] - lse, r[2] - lse, r[3] - lse);
      float4 o1 = make_float4(r[4] - lse, r[5] - lse, r[6] - lse, r[7] - lse);
      *(float4*)&out[v * OUT_CH + cg] = o0;
      *(float4*)&out[v * OUT_CH + cg + 4] = o1;
    }
  } else {
    if (slot == 0) {
      float4 o0 = make_float4(r[0] * disv, r[1] * disv, r[2] * disv, r[3] * disv);
      float4 o1 = make_float4(r[4] * disv, r[5] * disv, r[6] * disv, r[7] * disv);
      *(float4*)&out[v * OUT_CH + cg] = o0;
      *(float4*)&out[v * OUT_CH + cg + 4] = o1;
    }
  }
}

extern "C" void kernel_launch(void* const* d_in, const int* in_sizes, int n_in,
                              void* d_out, int out_size, void* d_ws, size_t ws_size,
                              hipStream_t stream) {
  const float* x = (const float*)d_in[0];
  const int* ei = (const int*)d_in[1];
  const float* W1 = (const float*)d_in[2];
  const float* b1 = (const float*)d_in[3];
  const float* W2 = (const float*)d_in[4];
  const float* b2 = (const float*)d_in[5];
  float* out = (float*)d_out;

  float* f = (float*)d_ws;                  // N*32
  float* gsa = f + (size_t)N_NODES * 32;    // N*32
  float* gsb = gsa + (size_t)N_NODES * 32;  // N*32
  int* deg = (int*)(gsb + (size_t)N_NODES * 32);  // N
  int* rowstart = deg + N_NODES;            // N
  int* adj = rowstart + N_NODES;            // 2E
  short* w1t = (short*)(adj + 2 * N_EDGES); // 512*64 bf16
  short* w2t = w1t + IN_CH * HID;           // 64*32 bf16
  int* blocksum = (int*)(w2t + HID * OUT_CH); // 512
  int* blockbase = blocksum + 512;          // 512
  int* pos = (int*)gsa;                     // 2E ints = 12.8MB overlay (dead after fill)

  hipMemsetAsync(deg, 0, N_NODES * sizeof(int), stream);
  k_prep<<<(IN_CH * HID + HID * OUT_CH + 255) / 256, 256, 0, stream>>>(W1, W2, w1t, w2t);
  k_hist<<<HSTRIDE / 256, 256, 0, stream>>>(ei, deg, pos);
  k_bsum<<<NB, 256, 0, stream>>>(deg, blocksum);
  k_scan1<<<1, 512, 0, stream>>>(blocksum, blockbase);
  k_rowstart<<<NB, 256, 0, stream>>>(deg, blockbase, rowstart);
  k_fill<<<HSTRIDE / 256, 256, 0, stream>>>(ei, pos, rowstart, adj);
  k_mlp<<<(N_NODES + 63) / 64, 256, 0, stream>>>(x, w1t, b1, w2t, b2, deg, f, gsa);
  k_prop<false><<<N_NODES / 4, 256, 0, stream>>>(gsa, f, deg, rowstart, adj, gsb);
  k_prop<true><<<N_NODES / 4, 256, 0, stream>>>(gsb, f, deg, rowstart, adj, out);
}

// Round 6
// 304.095 us; speedup vs baseline: 3.3277x; 1.3639x over previous
//
#include <hip/hip_runtime.h>
#include <hip/hip_bf16.h>
#include <math.h>

#define N_NODES 100000
#define N_EDGES 1600000
#define IN_CH 512
#define HID 64
#define OUT_CH 32
#define MU 0.1f
#define EPS 1e-8f

#define HE (2 * N_EDGES)    // 3.2M endpoints
#define ABLK 625            // scatter blocks
#define EPT 20              // endpoints per thread (625*256*20 = 3.2M)
#define NBUCK 391           // bucket = node >> 8 (256 nodes per bucket)

typedef short bf16x8 __attribute__((ext_vector_type(8)));
typedef float f32x4 __attribute__((ext_vector_type(4)));

__device__ __forceinline__ short f2bf(float f) {
  __hip_bfloat16 h = __float2bfloat16(f);
  return *reinterpret_cast<short*>(&h);
}

// ---------------- prep: W1 -> w1t[c][k] bf16, W2 -> w2t[c][k] bf16 ----------------
__global__ void k_prep(const float* __restrict__ W1, const float* __restrict__ W2,
                       short* __restrict__ w1t, short* __restrict__ w2t) {
  int i = blockIdx.x * 256 + threadIdx.x;
  if (i < IN_CH * HID) {
    int k = i / HID, c = i % HID;
    w1t[c * IN_CH + k] = f2bf(W1[i]);
  } else if (i < IN_CH * HID + HID * OUT_CH) {
    int j = i - IN_CH * HID;
    int k = j / OUT_CH, c = j % OUT_CH;
    w2t[c * HID + k] = f2bf(W2[j]);
  }
}

// ---------------- MLP via MFMA (unchanged from R4) ----------------
__global__ __launch_bounds__(256) void k_mlp(
    const float* __restrict__ x, const short* __restrict__ w1t,
    const float* __restrict__ b1, const short* __restrict__ w2t,
    const float* __restrict__ b2, const int* __restrict__ deg,
    float* __restrict__ f, float* __restrict__ gs) {
  __shared__ short ht[4][16][72];

  const int t = threadIdx.x;
  const int w = t >> 6;
  const int l = t & 63;
  const int lr = l & 15;
  const int kq = l >> 4;

  const int band = blockIdx.x * 64 + w * 16;
  const int gr = band + lr;
  const int grl = gr < N_NODES ? gr : N_NODES - 1;

  f32x4 acc1[4] = {};
  const float* xrow = x + (size_t)grl * IN_CH + kq * 8;
  #pragma unroll 4
  for (int ksub = 0; ksub < 16; ++ksub) {
    float4 alo = *(const float4*)(xrow + ksub * 32);
    float4 ahi = *(const float4*)(xrow + ksub * 32 + 4);
    bf16x8 a;
    a[0] = f2bf(alo.x); a[1] = f2bf(alo.y); a[2] = f2bf(alo.z); a[3] = f2bf(alo.w);
    a[4] = f2bf(ahi.x); a[5] = f2bf(ahi.y); a[6] = f2bf(ahi.z); a[7] = f2bf(ahi.w);
    #pragma unroll
    for (int ct = 0; ct < 4; ++ct) {
      const int c = ct * 16 + lr;
      bf16x8 b = *(const bf16x8*)&w1t[c * IN_CH + ksub * 32 + kq * 8];
      acc1[ct] = __builtin_amdgcn_mfma_f32_16x16x32_bf16(a, b, acc1[ct], 0, 0, 0);
    }
  }

  #pragma unroll
  for (int ct = 0; ct < 4; ++ct) {
    const int c = ct * 16 + lr;
    const float bb = b1[c];
    #pragma unroll
    for (int r = 0; r < 4; ++r) {
      float h = acc1[ct][r] + bb;
      ht[w][kq * 4 + r][c] = f2bf(h > 0.f ? h : 0.f);
    }
  }
  __syncthreads();

  f32x4 acc2[2] = {};
  #pragma unroll
  for (int ks = 0; ks < 2; ++ks) {
    bf16x8 a2 = *(const bf16x8*)&ht[w][lr][ks * 32 + kq * 8];
    #pragma unroll
    for (int ct = 0; ct < 2; ++ct) {
      const int c = ct * 16 + lr;
      bf16x8 b = *(const bf16x8*)&w2t[c * HID + ks * 32 + kq * 8];
      acc2[ct] = __builtin_amdgcn_mfma_f32_16x16x32_bf16(a2, b, acc2[ct], 0, 0, 0);
    }
  }

  #pragma unroll
  for (int r = 0; r < 4; ++r) {
    const int gr2 = band + kq * 4 + r;
    if (gr2 < N_NODES) {
      const int d = deg[gr2];
      const float di = d > 0 ? 1.0f / (float)d : 0.0f;
      const float disv = sqrtf(di);
      #pragma unroll
      for (int ct = 0; ct < 2; ++ct) {
        const int c = ct * 16 + lr;
        const float fv = acc2[ct][r] + b2[c];
        f[(size_t)gr2 * OUT_CH + c] = fv;
        gs[(size_t)gr2 * OUT_CH + c] = fv * disv;
      }
    }
  }
}

// ================= CSR build: bucketed counting sort, LDS atomics only =========
// A: per-(block,bucket) counts via LDS histogram
__global__ __launch_bounds__(256) void k_bcount(const int* __restrict__ ends,
                                                int* __restrict__ bcnt) {
  __shared__ int cnt[NBUCK];
  for (int i = threadIdx.x; i < NBUCK; i += 256) cnt[i] = 0;
  __syncthreads();
  const int base = blockIdx.x * (256 * EPT);
  #pragma unroll
  for (int j = 0; j < EPT; ++j) {
    int u = ends[base + j * 256 + threadIdx.x];
    atomicAdd(&cnt[u >> 8], 1);
  }
  __syncthreads();
  for (int i = threadIdx.x; i < NBUCK; i += 256) bcnt[i * ABLK + blockIdx.x] = cnt[i];
}

// B1: total per bucket
__global__ __launch_bounds__(256) void k_rowsum(const int* __restrict__ bcnt,
                                                int* __restrict__ btotal) {
  const int b = blockIdx.x;
  int s = 0;
  for (int i = threadIdx.x; i < ABLK; i += 256) s += bcnt[b * ABLK + i];
  #pragma unroll
  for (int k = 1; k < 64; k <<= 1) s += __shfl_xor(s, k);
  __shared__ int ws[4];
  if ((threadIdx.x & 63) == 0) ws[threadIdx.x >> 6] = s;
  __syncthreads();
  if (threadIdx.x == 0) btotal[b] = ws[0] + ws[1] + ws[2] + ws[3];
}

// B2: exclusive scan of 391 bucket totals
__global__ __launch_bounds__(512) void k_bscan(const int* __restrict__ btotal,
                                               int* __restrict__ bucketbase) {
  __shared__ int sh[512];
  const int t = threadIdx.x;
  int v = t < NBUCK ? btotal[t] : 0;
  sh[t] = v;
  __syncthreads();
  for (int s = 1; s < 512; s <<= 1) {
    int a = t >= s ? sh[t - s] : 0;
    __syncthreads();
    sh[t] += a;
    __syncthreads();
  }
  if (t < NBUCK) bucketbase[t] = sh[t] - v;
}

// B3: per bucket, exclusive scan over the 625 block counts -> scatter bases
// (written transposed: sbase[blk][bucket] so k_bscatter reads contiguous)
__global__ __launch_bounds__(256) void k_colscan(const int* __restrict__ bcnt,
                                                 const int* __restrict__ bucketbase,
                                                 int* __restrict__ sbase) {
  __shared__ int sh[256];
  const int b = blockIdx.x;
  const int t = threadIdx.x;
  int carry = bucketbase[b];
  for (int c = 0; c < ABLK; c += 256) {
    const int idx = c + t;
    int v = idx < ABLK ? bcnt[b * ABLK + idx] : 0;
    sh[t] = v;
    __syncthreads();
    for (int s = 1; s < 256; s <<= 1) {
      int a = t >= s ? sh[t - s] : 0;
      __syncthreads();
      sh[t] += a;
      __syncthreads();
    }
    if (idx < ABLK) sbase[idx * NBUCK + b] = carry + sh[t] - v;
    carry += sh[255];
    __syncthreads();
  }
}

// C: scatter (u, neighbor) pairs into bucket-grouped array (LDS cursors)
__global__ __launch_bounds__(256) void k_bscatter(const int* __restrict__ ends,
                                                  const int* __restrict__ sbase,
                                                  int2* __restrict__ pairs) {
  __shared__ int cur[NBUCK];
  for (int i = threadIdx.x; i < NBUCK; i += 256)
    cur[i] = sbase[blockIdx.x * NBUCK + i];
  __syncthreads();
  const int base = blockIdx.x * (256 * EPT);
  #pragma unroll
  for (int j = 0; j < EPT; ++j) {
    const int i = base + j * 256 + threadIdx.x;
    const int u = ends[i];
    const int nb = ends[i < N_EDGES ? i + N_EDGES : i - N_EDGES];
    const int slot = atomicAdd(&cur[u >> 8], 1);
    pairs[slot] = make_int2(u, nb);
  }
}

// D: per bucket (256 contiguous nodes): deg, rowstart, adj — all from LDS
__global__ __launch_bounds__(256) void k_csr(const int2* __restrict__ pairs,
                                             const int* __restrict__ bucketbase,
                                             const int* __restrict__ btotal,
                                             int* __restrict__ deg,
                                             int* __restrict__ rowstart,
                                             int* __restrict__ adj) {
  __shared__ int cnt[256];
  __shared__ int sh[256];
  const int b = blockIdx.x, t = threadIdx.x;
  const int v0 = b << 8;
  const int pbase = bucketbase[b];
  const int psz = btotal[b];
  cnt[t] = 0;
  __syncthreads();
  for (int i = t; i < psz; i += 256) atomicAdd(&cnt[pairs[pbase + i].x - v0], 1);
  __syncthreads();
  const int d = cnt[t];
  sh[t] = d;
  __syncthreads();
  for (int s = 1; s < 256; s <<= 1) {
    int a = t >= s ? sh[t - s] : 0;
    __syncthreads();
    sh[t] += a;
    __syncthreads();
  }
  const int rs = pbase + sh[t] - d;  // global rowstart
  const int v = v0 + t;
  if (v < N_NODES) {
    deg[v] = d;
    rowstart[v] = rs;
  }
  __syncthreads();
  cnt[t] = rs;  // reuse as cursor
  __syncthreads();
  for (int i = t; i < psz; i += 256) {
    const int2 p = pairs[pbase + i];
    adj[atomicAdd(&cnt[p.x - v0], 1)] = p.y;
  }
}

// ---------------- propagation iteration (unchanged from R4) ----------------
template <bool FINAL>
__global__ __launch_bounds__(256) void k_prop(
    const float* __restrict__ gs_in, const float* __restrict__ f,
    const int* __restrict__ deg, const int* __restrict__ rowstart,
    const int* __restrict__ adj, float* __restrict__ out) {
  const int v = blockIdx.x * 4 + (threadIdx.x >> 6);
  const int lane = threadIdx.x & 63;
  const int slot = lane >> 2;
  const int cg = (lane & 3) << 3;

  const float4 gv0 = *(const float4*)&gs_in[v * OUT_CH + cg];
  const float4 gv1 = *(const float4*)&gs_in[v * OUT_CH + cg + 4];

  const int dg = deg[v];
  const float dinvv = dg > 0 ? 1.0f / (float)dg : 0.0f;
  const float disv = sqrtf(dinvv);
  const int i0 = rowstart[v];

  float accs = 0.f;
  float acca[8] = {0.f, 0.f, 0.f, 0.f, 0.f, 0.f, 0.f, 0.f};

  for (int base = 0; base < dg; base += 16) {
    const int idx = base + slot;
    const bool valid = idx < dg;
    const int u = valid ? adj[i0 + idx] : v;
    const float4 gu0 = *(const float4*)&gs_in[u * OUT_CH + cg];
    const float4 gu1 = *(const float4*)&gs_in[u * OUT_CH + cg + 4];
    float d, sq;
    d = gv0.x - gu0.x; sq = d * d;
    d = gv0.y - gu0.y; sq = fmaf(d, d, sq);
    d = gv0.z - gu0.z; sq = fmaf(d, d, sq);
    d = gv0.w - gu0.w; sq = fmaf(d, d, sq);
    d = gv1.x - gu1.x; sq = fmaf(d, d, sq);
    d = gv1.y - gu1.y; sq = fmaf(d, d, sq);
    d = gv1.z - gu1.z; sq = fmaf(d, d, sq);
    d = gv1.w - gu1.w; sq = fmaf(d, d, sq);
    sq += __shfl_xor(sq, 1);
    sq += __shfl_xor(sq, 2);
    const float w = valid ? __frsqrt_rn(sqrtf(sq + EPS)) : 0.f;
    accs += w;
    acca[0] = fmaf(w, gu0.x, acca[0]);
    acca[1] = fmaf(w, gu0.y, acca[1]);
    acca[2] = fmaf(w, gu0.z, acca[2]);
    acca[3] = fmaf(w, gu0.w, acca[3]);
    acca[4] = fmaf(w, gu1.x, acca[4]);
    acca[5] = fmaf(w, gu1.y, acca[5]);
    acca[6] = fmaf(w, gu1.z, acca[6]);
    acca[7] = fmaf(w, gu1.w, acca[7]);
  }

  #pragma unroll
  for (int s = 4; s <= 32; s <<= 1) {
    accs += __shfl_xor(accs, s);
    #pragma unroll
    for (int j = 0; j < 8; ++j) acca[j] += __shfl_xor(acca[j], s);
  }

  const float alpha = 1.0f / (accs * dinvv + MU);
  const float ad = alpha * disv;
  const float ba = MU * alpha;
  const float4 fv0 = *(const float4*)&f[v * OUT_CH + cg];
  const float4 fv1 = *(const float4*)&f[v * OUT_CH + cg + 4];
  float r[8];
  r[0] = fmaf(ad, acca[0], ba * fv0.x);
  r[1] = fmaf(ad, acca[1], ba * fv0.y);
  r[2] = fmaf(ad, acca[2], ba * fv0.z);
  r[3] = fmaf(ad, acca[3], ba * fv0.w);
  r[4] = fmaf(ad, acca[4], ba * fv1.x);
  r[5] = fmaf(ad, acca[5], ba * fv1.y);
  r[6] = fmaf(ad, acca[6], ba * fv1.z);
  r[7] = fmaf(ad, acca[7], ba * fv1.w);

  if (FINAL) {
    float m = r[0];
    #pragma unroll
    for (int j = 1; j < 8; ++j) m = fmaxf(m, r[j]);
    m = fmaxf(m, __shfl_xor(m, 1));
    m = fmaxf(m, __shfl_xor(m, 2));
    float se = 0.f;
    #pragma unroll
    for (int j = 0; j < 8; ++j) se += __expf(r[j] - m);
    se += __shfl_xor(se, 1);
    se += __shfl_xor(se, 2);
    const float lse = m + __logf(se);
    if (slot == 0) {
      float4 o0 = make_float4(r[0] - lse, r[1] - lse, r[2] - lse, r[3] - lse);
      float4 o1 = make_float4(r[4] - lse, r[5] - lse, r[6] - lse, r[7] - lse);
      *(float4*)&out[v * OUT_CH + cg] = o0;
      *(float4*)&out[v * OUT_CH + cg + 4] = o1;
    }
  } else {
    if (slot == 0) {
      float4 o0 = make_float4(r[0] * disv, r[1] * disv, r[2] * disv, r[3] * disv);
      float4 o1 = make_float4(r[4] * disv, r[5] * disv, r[6] * disv, r[7] * disv);
      *(float4*)&out[v * OUT_CH + cg] = o0;
      *(float4*)&out[v * OUT_CH + cg + 4] = o1;
    }
  }
}

extern "C" void kernel_launch(void* const* d_in, const int* in_sizes, int n_in,
                              void* d_out, int out_size, void* d_ws, size_t ws_size,
                              hipStream_t stream) {
  const float* x = (const float*)d_in[0];
  const int* ei = (const int*)d_in[1];  // [src(1.6M); dst(1.6M)] = 3.2M endpoints
  const float* W1 = (const float*)d_in[2];
  const float* b1 = (const float*)d_in[3];
  const float* W2 = (const float*)d_in[4];
  const float* b2 = (const float*)d_in[5];
  float* out = (float*)d_out;

  float* f = (float*)d_ws;                        // N*32 f32
  float* gsa = f + (size_t)N_NODES * 32;          // N*32
  float* gsb = gsa + (size_t)N_NODES * 32;        // N*32
  int* deg = (int*)(gsb + (size_t)N_NODES * 32);  // N
  int* rowstart = deg + N_NODES;                  // N
  int* adj = rowstart + N_NODES;                  // 2E
  short* w1t = (short*)(adj + 2 * N_EDGES);       // 512*64 bf16
  short* w2t = w1t + IN_CH * HID;                 // 64*32 bf16
  int* bcnt = (int*)(w2t + HID * OUT_CH);         // NBUCK*ABLK
  int* sbase = bcnt + NBUCK * ABLK;               // ABLK*NBUCK (transposed)
  int* btotal = sbase + NBUCK * ABLK;             // NBUCK
  int* bucketbase = btotal + NBUCK + 1;           // NBUCK
  // pairs (2E int2 = 25.6MB) overlays gsa+gsb (dead until k_mlp)
  int2* pairs = (int2*)gsa;

  k_prep<<<(IN_CH * HID + HID * OUT_CH + 255) / 256, 256, 0, stream>>>(W1, W2, w1t, w2t);
  k_bcount<<<ABLK, 256, 0, stream>>>(ei, bcnt);
  k_rowsum<<<NBUCK, 256, 0, stream>>>(bcnt, btotal);
  k_bscan<<<1, 512, 0, stream>>>(btotal, bucketbase);
  k_colscan<<<NBUCK, 256, 0, stream>>>(bcnt, bucketbase, sbase);
  k_bscatter<<<ABLK, 256, 0, stream>>>(ei, sbase, pairs);
  k_csr<<<NBUCK, 256, 0, stream>>>(pairs, bucketbase, btotal, deg, rowstart, adj);
  k_mlp<<<(N_NODES + 63) / 64, 256, 0, stream>>>(x, w1t, b1, w2t, b2, deg, f, gsa);
  k_prop<false><<<N_NODES / 4, 256, 0, stream>>>(gsa, f, deg, rowstart, adj, gsb);
  k_prop<true><<<N_NODES / 4, 256, 0, stream>>>(gsb, f, deg, rowstart, adj, out);
}

// Round 7
// 291.401 us; speedup vs baseline: 3.4727x; 1.0436x over previous
//
#include <hip/hip_runtime.h>
#include <hip/hip_bf16.h>
#include <math.h>

#define N_NODES 100000
#define N_EDGES 1600000
#define IN_CH 512
#define HID 64
#define OUT_CH 32
#define MU 0.1f
#define EPS 1e-8f

#define HE (2 * N_EDGES)    // 3.2M endpoints
#define ABLK 625            // scatter blocks
#define EPT 20              // endpoints per thread (625*256*20 = 3.2M)
#define NBUCK 391           // bucket = node >> 8 (256 nodes per bucket)

typedef short bf16x8 __attribute__((ext_vector_type(8)));
typedef unsigned short us8 __attribute__((ext_vector_type(8)));
typedef float f32x4 __attribute__((ext_vector_type(4)));

__device__ __forceinline__ short f2bf(float f) {
  __hip_bfloat16 h = __float2bfloat16(f);
  return *reinterpret_cast<short*>(&h);
}
__device__ __forceinline__ float bf2f(unsigned short u) {
  unsigned int b = ((unsigned int)u) << 16;
  return __uint_as_float(b);
}

// ---------------- prep: W1 -> w1t[c][k] bf16, W2 -> w2t[c][k] bf16 ----------------
__global__ void k_prep(const float* __restrict__ W1, const float* __restrict__ W2,
                       short* __restrict__ w1t, short* __restrict__ w2t) {
  int i = blockIdx.x * 256 + threadIdx.x;
  if (i < IN_CH * HID) {
    int k = i / HID, c = i % HID;
    w1t[c * IN_CH + k] = f2bf(W1[i]);
  } else if (i < IN_CH * HID + HID * OUT_CH) {
    int j = i - IN_CH * HID;
    int k = j / OUT_CH, c = j % OUT_CH;
    w2t[c * HID + k] = f2bf(W2[j]);
  }
}

// ---------------- MLP via MFMA; epilogue writes f (fp32) and gs (bf16) --------
__global__ __launch_bounds__(256) void k_mlp(
    const float* __restrict__ x, const short* __restrict__ w1t,
    const float* __restrict__ b1, const short* __restrict__ w2t,
    const float* __restrict__ b2, const int* __restrict__ deg,
    float* __restrict__ f, unsigned short* __restrict__ gs) {
  __shared__ short ht[4][16][72];

  const int t = threadIdx.x;
  const int w = t >> 6;
  const int l = t & 63;
  const int lr = l & 15;
  const int kq = l >> 4;

  const int band = blockIdx.x * 64 + w * 16;
  const int gr = band + lr;
  const int grl = gr < N_NODES ? gr : N_NODES - 1;

  f32x4 acc1[4] = {};
  const float* xrow = x + (size_t)grl * IN_CH + kq * 8;
  #pragma unroll 4
  for (int ksub = 0; ksub < 16; ++ksub) {
    float4 alo = *(const float4*)(xrow + ksub * 32);
    float4 ahi = *(const float4*)(xrow + ksub * 32 + 4);
    bf16x8 a;
    a[0] = f2bf(alo.x); a[1] = f2bf(alo.y); a[2] = f2bf(alo.z); a[3] = f2bf(alo.w);
    a[4] = f2bf(ahi.x); a[5] = f2bf(ahi.y); a[6] = f2bf(ahi.z); a[7] = f2bf(ahi.w);
    #pragma unroll
    for (int ct = 0; ct < 4; ++ct) {
      const int c = ct * 16 + lr;
      bf16x8 b = *(const bf16x8*)&w1t[c * IN_CH + ksub * 32 + kq * 8];
      acc1[ct] = __builtin_amdgcn_mfma_f32_16x16x32_bf16(a, b, acc1[ct], 0, 0, 0);
    }
  }

  #pragma unroll
  for (int ct = 0; ct < 4; ++ct) {
    const int c = ct * 16 + lr;
    const float bb = b1[c];
    #pragma unroll
    for (int r = 0; r < 4; ++r) {
      float h = acc1[ct][r] + bb;
      ht[w][kq * 4 + r][c] = f2bf(h > 0.f ? h : 0.f);
    }
  }
  __syncthreads();

  f32x4 acc2[2] = {};
  #pragma unroll
  for (int ks = 0; ks < 2; ++ks) {
    bf16x8 a2 = *(const bf16x8*)&ht[w][lr][ks * 32 + kq * 8];
    #pragma unroll
    for (int ct = 0; ct < 2; ++ct) {
      const int c = ct * 16 + lr;
      bf16x8 b = *(const bf16x8*)&w2t[c * HID + ks * 32 + kq * 8];
      acc2[ct] = __builtin_amdgcn_mfma_f32_16x16x32_bf16(a2, b, acc2[ct], 0, 0, 0);
    }
  }

  #pragma unroll
  for (int r = 0; r < 4; ++r) {
    const int gr2 = band + kq * 4 + r;
    if (gr2 < N_NODES) {
      const int d = deg[gr2];
      const float di = d > 0 ? 1.0f / (float)d : 0.0f;
      const float disv = sqrtf(di);
      #pragma unroll
      for (int ct = 0; ct < 2; ++ct) {
        const int c = ct * 16 + lr;
        const float fv = acc2[ct][r] + b2[c];
        f[(size_t)gr2 * OUT_CH + c] = fv;
        gs[(size_t)gr2 * OUT_CH + c] = (unsigned short)f2bf(fv * disv);
      }
    }
  }
}

// ================= CSR build: bucketed counting sort, LDS atomics only =========
__global__ __launch_bounds__(256) void k_bcount(const int* __restrict__ ends,
                                                int* __restrict__ bcnt) {
  __shared__ int cnt[NBUCK];
  for (int i = threadIdx.x; i < NBUCK; i += 256) cnt[i] = 0;
  __syncthreads();
  const int base = blockIdx.x * (256 * EPT);
  #pragma unroll
  for (int j = 0; j < EPT; ++j) {
    int u = ends[base + j * 256 + threadIdx.x];
    atomicAdd(&cnt[u >> 8], 1);
  }
  __syncthreads();
  for (int i = threadIdx.x; i < NBUCK; i += 256) bcnt[i * ABLK + blockIdx.x] = cnt[i];
}

__global__ __launch_bounds__(256) void k_rowsum(const int* __restrict__ bcnt,
                                                int* __restrict__ btotal) {
  const int b = blockIdx.x;
  int s = 0;
  for (int i = threadIdx.x; i < ABLK; i += 256) s += bcnt[b * ABLK + i];
  #pragma unroll
  for (int k = 1; k < 64; k <<= 1) s += __shfl_xor(s, k);
  __shared__ int ws[4];
  if ((threadIdx.x & 63) == 0) ws[threadIdx.x >> 6] = s;
  __syncthreads();
  if (threadIdx.x == 0) btotal[b] = ws[0] + ws[1] + ws[2] + ws[3];
}

__global__ __launch_bounds__(512) void k_bscan(const int* __restrict__ btotal,
                                               int* __restrict__ bucketbase) {
  __shared__ int sh[512];
  const int t = threadIdx.x;
  int v = t < NBUCK ? btotal[t] : 0;
  sh[t] = v;
  __syncthreads();
  for (int s = 1; s < 512; s <<= 1) {
    int a = t >= s ? sh[t - s] : 0;
    __syncthreads();
    sh[t] += a;
    __syncthreads();
  }
  if (t < NBUCK) bucketbase[t] = sh[t] - v;
}

__global__ __launch_bounds__(256) void k_colscan(const int* __restrict__ bcnt,
                                                 const int* __restrict__ bucketbase,
                                                 int* __restrict__ sbase) {
  __shared__ int sh[256];
  const int b = blockIdx.x;
  const int t = threadIdx.x;
  int carry = bucketbase[b];
  for (int c = 0; c < ABLK; c += 256) {
    const int idx = c + t;
    int v = idx < ABLK ? bcnt[b * ABLK + idx] : 0;
    sh[t] = v;
    __syncthreads();
    for (int s = 1; s < 256; s <<= 1) {
      int a = t >= s ? sh[t - s] : 0;
      __syncthreads();
      sh[t] += a;
      __syncthreads();
    }
    if (idx < ABLK) sbase[idx * NBUCK + b] = carry + sh[t] - v;
    carry += sh[255];
    __syncthreads();
  }
}

// C: scatter packed (u_local<<24 | nb) into bucket-grouped array (LDS cursors)
__global__ __launch_bounds__(256) void k_bscatter(const int* __restrict__ ends,
                                                  const int* __restrict__ sbase,
                                                  int* __restrict__ pairs) {
  __shared__ int cur[NBUCK];
  for (int i = threadIdx.x; i < NBUCK; i += 256)
    cur[i] = sbase[blockIdx.x * NBUCK + i];
  __syncthreads();
  const int base = blockIdx.x * (256 * EPT);
  #pragma unroll
  for (int j = 0; j < EPT; ++j) {
    const int i = base + j * 256 + threadIdx.x;
    const int u = ends[i];
    const int nb = ends[i < N_EDGES ? i + N_EDGES : i - N_EDGES];
    const int slot = atomicAdd(&cur[u >> 8], 1);
    pairs[slot] = ((u & 255) << 24) | nb;
  }
}

// D: per bucket (256 contiguous nodes): deg, rowstart, adj — all from LDS
__global__ __launch_bounds__(256) void k_csr(const int* __restrict__ pairs,
                                             const int* __restrict__ bucketbase,
                                             const int* __restrict__ btotal,
                                             int* __restrict__ deg,
                                             int* __restrict__ rowstart,
                                             int* __restrict__ adj) {
  __shared__ int cnt[256];
  __shared__ int sh[256];
  const int b = blockIdx.x, t = threadIdx.x;
  const int pbase = bucketbase[b];
  const int psz = btotal[b];
  cnt[t] = 0;
  __syncthreads();
  for (int i = t; i < psz; i += 256)
    atomicAdd(&cnt[((unsigned)pairs[pbase + i]) >> 24], 1);
  __syncthreads();
  const int d = cnt[t];
  sh[t] = d;
  __syncthreads();
  for (int s = 1; s < 256; s <<= 1) {
    int a = t >= s ? sh[t - s] : 0;
    __syncthreads();
    sh[t] += a;
    __syncthreads();
  }
  const int rs = pbase + sh[t] - d;
  const int v = (b << 8) + t;
  if (v < N_NODES) {
    deg[v] = d;
    rowstart[v] = rs;
  }
  __syncthreads();
  cnt[t] = rs;
  __syncthreads();
  for (int i = t; i < psz; i += 256) {
    const int p = pairs[pbase + i];
    adj[atomicAdd(&cnt[((unsigned)p) >> 24], 1)] = p & 0xFFFFFF;
  }
}

// ---------------- propagation (bf16 gs gather, fp32 accumulate) ----------------
template <bool FINAL>
__global__ __launch_bounds__(256) void k_prop(
    const unsigned short* __restrict__ gs_in, const float* __restrict__ f,
    const int* __restrict__ deg, const int* __restrict__ rowstart,
    const int* __restrict__ adj, float* __restrict__ outf,
    unsigned short* __restrict__ outg) {
  const int v = blockIdx.x * 4 + (threadIdx.x >> 6);
  const int lane = threadIdx.x & 63;
  const int slot = lane >> 2;
  const int cg = (lane & 3) << 3;

  const us8 gvu = *(const us8*)&gs_in[v * OUT_CH + cg];
  float gv[8];
  #pragma unroll
  for (int j = 0; j < 8; ++j) gv[j] = bf2f(gvu[j]);

  const int dg = deg[v];
  const float dinvv = dg > 0 ? 1.0f / (float)dg : 0.0f;
  const float disv = sqrtf(dinvv);
  const int i0 = rowstart[v];

  float accs = 0.f;
  float acca[8] = {0.f, 0.f, 0.f, 0.f, 0.f, 0.f, 0.f, 0.f};

  for (int base = 0; base < dg; base += 16) {
    const int idx = base + slot;
    const bool valid = idx < dg;
    const int u = valid ? adj[i0 + idx] : v;
    const us8 guu = *(const us8*)&gs_in[u * OUT_CH + cg];
    float gu[8];
    #pragma unroll
    for (int j = 0; j < 8; ++j) gu[j] = bf2f(guu[j]);
    float d, sq;
    d = gv[0] - gu[0]; sq = d * d;
    #pragma unroll
    for (int j = 1; j < 8; ++j) { d = gv[j] - gu[j]; sq = fmaf(d, d, sq); }
    sq += __shfl_xor(sq, 1);
    sq += __shfl_xor(sq, 2);
    const float w = valid ? __frsqrt_rn(sqrtf(sq + EPS)) : 0.f;
    accs += w;
    #pragma unroll
    for (int j = 0; j < 8; ++j) acca[j] = fmaf(w, gu[j], acca[j]);
  }

  #pragma unroll
  for (int s = 4; s <= 32; s <<= 1) {
    accs += __shfl_xor(accs, s);
    #pragma unroll
    for (int j = 0; j < 8; ++j) acca[j] += __shfl_xor(acca[j], s);
  }

  const float alpha = 1.0f / (accs * dinvv + MU);
  const float ad = alpha * disv;
  const float ba = MU * alpha;
  const float4 fv0 = *(const float4*)&f[v * OUT_CH + cg];
  const float4 fv1 = *(const float4*)&f[v * OUT_CH + cg + 4];
  float r[8];
  r[0] = fmaf(ad, acca[0], ba * fv0.x);
  r[1] = fmaf(ad, acca[1], ba * fv0.y);
  r[2] = fmaf(ad, acca[2], ba * fv0.z);
  r[3] = fmaf(ad, acca[3], ba * fv0.w);
  r[4] = fmaf(ad, acca[4], ba * fv1.x);
  r[5] = fmaf(ad, acca[5], ba * fv1.y);
  r[6] = fmaf(ad, acca[6], ba * fv1.z);
  r[7] = fmaf(ad, acca[7], ba * fv1.w);

  if (FINAL) {
    float m = r[0];
    #pragma unroll
    for (int j = 1; j < 8; ++j) m = fmaxf(m, r[j]);
    m = fmaxf(m, __shfl_xor(m, 1));
    m = fmaxf(m, __shfl_xor(m, 2));
    float se = 0.f;
    #pragma unroll
    for (int j = 0; j < 8; ++j) se += __expf(r[j] - m);
    se += __shfl_xor(se, 1);
    se += __shfl_xor(se, 2);
    const float lse = m + __logf(se);
    if (slot == 0) {
      float4 o0 = make_float4(r[0] - lse, r[1] - lse, r[2] - lse, r[3] - lse);
      float4 o1 = make_float4(r[4] - lse, r[5] - lse, r[6] - lse, r[7] - lse);
      *(float4*)&outf[v * OUT_CH + cg] = o0;
      *(float4*)&outf[v * OUT_CH + cg + 4] = o1;
    }
  } else {
    if (slot == 0) {
      us8 o;
      #pragma unroll
      for (int j = 0; j < 8; ++j) o[j] = (unsigned short)f2bf(r[j] * disv);
      *(us8*)&outg[v * OUT_CH + cg] = o;
    }
  }
}

extern "C" void kernel_launch(void* const* d_in, const int* in_sizes, int n_in,
                              void* d_out, int out_size, void* d_ws, size_t ws_size,
                              hipStream_t stream) {
  const float* x = (const float*)d_in[0];
  const int* ei = (const int*)d_in[1];  // [src(1.6M); dst(1.6M)]
  const float* W1 = (const float*)d_in[2];
  const float* b1 = (const float*)d_in[3];
  const float* W2 = (const float*)d_in[4];
  const float* b2 = (const float*)d_in[5];
  float* out = (float*)d_out;

  float* f = (float*)d_ws;                             // N*32 f32 (12.8MB)
  unsigned short* gsa = (unsigned short*)(f + (size_t)N_NODES * 32);  // N*32 bf16
  unsigned short* gsb = gsa + (size_t)N_NODES * 32;    // N*32 bf16
  int* deg = (int*)(gsb + (size_t)N_NODES * 32);       // N
  int* rowstart = deg + N_NODES;                       // N
  int* adj = rowstart + N_NODES;                       // 2E
  short* w1t = (short*)(adj + 2 * N_EDGES);            // 512*64 bf16
  short* w2t = w1t + IN_CH * HID;                      // 64*32 bf16
  int* bcnt = (int*)(w2t + HID * OUT_CH);              // NBUCK*ABLK
  int* sbase = bcnt + NBUCK * ABLK;                    // ABLK*NBUCK (transposed)
  int* btotal = sbase + NBUCK * ABLK;                  // NBUCK
  int* bucketbase = btotal + NBUCK + 1;                // NBUCK
  // packed pairs (2E ints = 12.8MB) overlays f (dead until k_mlp)
  int* pairs = (int*)f;

  k_prep<<<(IN_CH * HID + HID * OUT_CH + 255) / 256, 256, 0, stream>>>(W1, W2, w1t, w2t);
  k_bcount<<<ABLK, 256, 0, stream>>>(ei, bcnt);
  k_rowsum<<<NBUCK, 256, 0, stream>>>(bcnt, btotal);
  k_bscan<<<1, 512, 0, stream>>>(btotal, bucketbase);
  k_colscan<<<NBUCK, 256, 0, stream>>>(bcnt, bucketbase, sbase);
  k_bscatter<<<ABLK, 256, 0, stream>>>(ei, sbase, pairs);
  k_csr<<<NBUCK, 256, 0, stream>>>(pairs, bucketbase, btotal, deg, rowstart, adj);
  k_mlp<<<(N_NODES + 63) / 64, 256, 0, stream>>>(x, w1t, b1, w2t, b2, deg, f, gsa);
  k_prop<false><<<N_NODES / 4, 256, 0, stream>>>(gsa, f, deg, rowstart, adj, nullptr, gsb);
  k_prop<true><<<N_NODES / 4, 256, 0, stream>>>(gsb, f, deg, rowstart, adj, out, nullptr);
}